// Round 11
// baseline (291.729 us; speedup 1.0000x reference)
//
#include <hip/hip_runtime.h>

// DiagLRConv: out[n,o,h,w] = sum_{k,i} fw[o,i,k] * x[n,i,h+k-2,w+k-2]
// x: (16,16,512,512) fp32, fw: (16,16,5) fp32, out fp32.
//
// R11: single fused kernel.
//  1) Stage fp32 NCHW tile -> LDS via global_load_lds width-16 (issue-parallel,
//     compiler cannot serialize: the R4/R6/R7/R9 failure mode).
//     fp32 region: site (ch, ri, cq) = 16B = 4 w-px of one channel.
//  2) In-LDS channel transpose + bf16 cvt: 240 threads, each reads 8 ch-quads
//     (ds_read_b128) and writes 4 bf16 fragment sites (8 ch at one px).
//  3) Hot loop: 3 ds_read_b128 + 3 mfma_f32_16x16x32_bf16 + 1 dwordx4 store
//     per 16x16 tile. Mappings verified R5-R10.
// Borders: staging clamps (wrong halo data) -> border outputs recomputed
// exactly by fixup kernel (proven R8).

#define HH    512
#define WW    512
#define CH    16
#define KK    5
#define IMG   (HH * WW)
#define CHIMG (CH * IMG)

#define HT 8              // output rows per block
#define WT 32             // output px per block
#define RI 12             // staged rows (HT + 4)
#define WCI 36            // bf16 staged cols (WT + 4)
#define NCQ 10            // fp32 staged col-quads ([w0-4, w0+36))
#define NF32SITE (CH * RI * NCQ)        // 1920 16B sites (= 30 gload16)
#define NB16SITE (2 * RI * WCI)         // 864 16B sites
#define NLD      (NF32SITE / 64)        // 30 gload_lds16 per block

typedef __attribute__((ext_vector_type(8))) short bf16x8;
typedef __attribute__((ext_vector_type(4))) float f32x4;
typedef __attribute__((ext_vector_type(4))) int   i32x4;

union I4S8 { i32x4 i; bf16x8 s; };
union I4F4 { i32x4 i; f32x4 f; };

__device__ __forceinline__ unsigned cvt_pk_bf16(float lo, float hi) {
    unsigned r;
    asm("v_cvt_pk_bf16_f32 %0, %1, %2" : "=v"(r) : "v"(lo), "v"(hi));
    return r;
}

// NOTE (R2): never cap VGPRs via __launch_bounds__ min-waves — acc spills.
__global__ __launch_bounds__(256)
void diag_conv_fused(const float* __restrict__ x,
                     const float* __restrict__ fw,
                     float* __restrict__ out)
{
    // [0,1920): fp32 sites (ch*RI + ri)*NCQ + cq
    // [1920, 2784): bf16 sites 1920 + (ihl*RI + ri)*WCI + ci
    __shared__ i32x4 xl[NF32SITE + NB16SITE];   // 44544 B -> 3 blocks/CU

    const int tid  = threadIdx.x;
    const int wv   = tid >> 6;
    const int lane = tid & 63;

    // Bijective XCD swizzle: 16384 blocks = 8 XCDs x 2048 contiguous (2 images).
    const int bid = blockIdx.x;
    const int swz = ((bid & 7) << 11) | (bid >> 3);
    const int n  = swz >> 10;         // 0..15
    const int ht = (swz >> 4) & 63;   // 0..63
    const int wt = swz & 15;          // 0..15
    const int h0 = ht * HT;
    const int w0 = wt * WT;

    const float* __restrict__ xn = x + (size_t)n * CHIMG;

    // ---- phase 1: stage fp32 tile via 30x global_load_lds width-16 ---------
    // site s = (ch*RI + ri)*NCQ + cq ; global (r,wq) clamped (borders fixed up)
#pragma unroll
    for (int uu = 0; uu < 8; ++uu) {
        const int u = uu * 4 + wv;               // wave-uniform
        if (u < NLD) {
            const int s   = u * 64 + lane;       // 0..1919 exact
            const int ch  = s / (RI * NCQ);
            const int rem = s - ch * (RI * NCQ);
            const int ri  = rem / NCQ;
            const int cq  = rem - ri * NCQ;
            int r = h0 - 2 + ri;
            r = r < 0 ? 0 : (r > HH - 1 ? HH - 1 : r);
            int wq = w0 - 4 + 4 * cq;
            wq = wq < 0 ? 0 : (wq > WW - 4 ? WW - 4 : wq);
            const float* src = xn + (size_t)ch * IMG + (size_t)r * WW + wq;
            __builtin_amdgcn_global_load_lds(
                (const __attribute__((address_space(1))) void*)src,
                (__attribute__((address_space(3))) void*)(xl + u * 64), 16, 0, 0);
        }
    }

    // ---- W fragments (B operand) — verified R5-R10. tap==5 -> zero ---------
    const int px  = lane & 15;
    const int ihl = (lane >> 4) & 1;
    const int tb  = lane >> 5;

    bf16x8 wfrag[3];
#pragma unroll
    for (int s = 0; s < 3; ++s) {
        const int tap = 2 * s + tb;
        I4S8 a;
        a.i = (i32x4){0, 0, 0, 0};
        if (tap < KK) {
            const float* __restrict__ wp = fw + ((size_t)px * CH + ihl * 8) * KK + tap;
            a.i.x = (int)cvt_pk_bf16(wp[0 * KK], wp[1 * KK]);
            a.i.y = (int)cvt_pk_bf16(wp[2 * KK], wp[3 * KK]);
            a.i.z = (int)cvt_pk_bf16(wp[4 * KK], wp[5 * KK]);
            a.i.w = (int)cvt_pk_bf16(wp[6 * KK], wp[7 * KK]);
        }
        wfrag[s] = a.s;
    }

    __syncthreads();   // drain gload_lds

    // ---- phase 2: in-LDS channel transpose + bf16 cvt ----------------------
    // thread (ihl, ri, cq): read 8 ch-quads, emit 4 bf16 sites (ci = 4cq-2+p)
    if (tid < 2 * RI * NCQ) {                    // 240 threads
        const int ihl2 = tid / (RI * NCQ);
        const int rem  = tid - ihl2 * (RI * NCQ);
        const int ri   = rem / NCQ;
        const int cq   = rem - ri * NCQ;
        I4F4 v[8];
#pragma unroll
        for (int j = 0; j < 8; ++j)
            v[j].i = xl[((ihl2 * 8 + j) * RI + ri) * NCQ + cq];
#pragma unroll
        for (int p = 0; p < 4; ++p) {
            const int ci = 4 * cq - 2 + p;
            if ((unsigned)ci < (unsigned)WCI) {
                i32x4 pk;
                pk.x = (int)cvt_pk_bf16(v[0].f[p], v[1].f[p]);
                pk.y = (int)cvt_pk_bf16(v[2].f[p], v[3].f[p]);
                pk.z = (int)cvt_pk_bf16(v[4].f[p], v[5].f[p]);
                pk.w = (int)cvt_pk_bf16(v[6].f[p], v[7].f[p]);
                xl[NF32SITE + (ihl2 * RI + ri) * WCI + ci] = pk;
            }
        }
    }

    __syncthreads();

    // ---- phase 3: hot loop — per wave 2 h-rows x 2 w-tiles -----------------
    float* __restrict__ outn = out + (size_t)n * CHIMG;
    const int o  = lane & 15;
    const int pq = (lane >> 4) << 2;
    const int ib = NF32SITE + ihl * (RI * WCI);

#pragma unroll
    for (int rr = 0; rr < 2; ++rr) {
        const int rloc = wv * 2 + rr;
        const int h    = h0 + rloc;
#pragma unroll
        for (int g = 0; g < 2; ++g) {
            f32x4 acc = (f32x4){0.f, 0.f, 0.f, 0.f};
#pragma unroll
            for (int s = 0; s < 3; ++s) {
                const int tap = 2 * s + tb;
                int ri = rloc + tap;
                ri = ri > RI - 1 ? RI - 1 : ri;       // tap-5 pad lanes only
                int ci = g * 16 + px + tap;
                ci = ci > WCI - 1 ? WCI - 1 : ci;     // tap-5 pad lanes only
                I4S8 b;
                b.i = xl[ib + ri * WCI + ci];
                acc = __builtin_amdgcn_mfma_f32_16x16x32_bf16(
                    b.s, wfrag[s], acc, 0, 0, 0);
            }
            *(f32x4*)(outn + (size_t)o * IMG + (size_t)h * WW +
                      (w0 + g * 16 + pq)) = acc;
        }
    }
}

// ---------------- fixup: recompute outputs with h or w in {0,1,510,511} -----
__global__ __launch_bounds__(256)
void diag_conv_fixup(const float* __restrict__ x,
                     const float* __restrict__ fw,
                     float* __restrict__ out)
{
    __shared__ __align__(16) float Wl[KK][CH][CH];   // [k][i][o]
    const int tid = threadIdx.x;
    for (int idx = tid; idx < KK * CH * CH; idx += 256) {
        int k   = idx >> 8;
        int rem = idx & 255;
        int i   = rem >> 4;
        int o   = rem & 15;
        Wl[k][i][o] = fw[(o * CH + i) * KK + k];
    }
    __syncthreads();

    const int n = blockIdx.y;
    const int s = blockIdx.x * 256 + tid;
    if (s >= 4080) return;

    int h, w;
    if (s < 2048) {                        // h-border rows, all w
        const int c = s >> 9;
        h = c < 2 ? c : 508 + c;           // 0,1,510,511
        w = s & 511;
    } else {                               // w-border cols, h in [2,509]
        const int s2 = s - 2048;
        const int c  = s2 / 508;
        w = c < 2 ? c : 508 + c;
        h = 2 + s2 % 508;
    }

    f32x4 acc4[4];
#pragma unroll
    for (int u = 0; u < 4; ++u) acc4[u] = (f32x4){0.f, 0.f, 0.f, 0.f};

#pragma unroll
    for (int k = 0; k < KK; ++k) {
        const int hh = h + k - 2;
        const int ww = w + k - 2;
        if ((unsigned)hh >= (unsigned)HH || (unsigned)ww >= (unsigned)WW) continue;
        const float* __restrict__ xp = x + (size_t)n * CHIMG + (size_t)hh * WW + ww;
#pragma unroll
        for (int i = 0; i < CH; ++i) {
            const float xi = xp[(size_t)i * IMG];
#pragma unroll
            for (int u = 0; u < 4; ++u) {
                const f32x4 w4 = *(const f32x4*)&Wl[k][i][4 * u];
                acc4[u].x = fmaf(w4.x, xi, acc4[u].x);
                acc4[u].y = fmaf(w4.y, xi, acc4[u].y);
                acc4[u].z = fmaf(w4.z, xi, acc4[u].z);
                acc4[u].w = fmaf(w4.w, xi, acc4[u].w);
            }
        }
    }

#pragma unroll
    for (int u = 0; u < 4; ++u) {
        out[(size_t)(n * CH + 4 * u + 0) * IMG + (size_t)h * WW + w] = acc4[u].x;
        out[(size_t)(n * CH + 4 * u + 1) * IMG + (size_t)h * WW + w] = acc4[u].y;
        out[(size_t)(n * CH + 4 * u + 2) * IMG + (size_t)h * WW + w] = acc4[u].z;
        out[(size_t)(n * CH + 4 * u + 3) * IMG + (size_t)h * WW + w] = acc4[u].w;
    }
}

extern "C" void kernel_launch(void* const* d_in, const int* in_sizes, int n_in,
                              void* d_out, int out_size, void* d_ws, size_t ws_size,
                              hipStream_t stream)
{
    const float* x  = (const float*)d_in[0];
    const float* fw = (const float*)d_in[1];
    float* out      = (float*)d_out;

    // 16384 blocks = 16 n x 64 ht x 16 wt
    diag_conv_fused<<<dim3(16384), dim3(256), 0, stream>>>(x, fw, out);
    diag_conv_fixup<<<dim3(16, 16), dim3(256), 0, stream>>>(x, fw, out);
}

// Round 12
// 157.068 us; speedup vs baseline: 1.8573x; 1.8573x over previous
//
#include <hip/hip_runtime.h>

// DiagLRConv: out[n,o,h,w] = sum_{k,i} fw[o,i,k] * x[n,i,h+k-2,w+k-2]
// x: (16,16,512,512) fp32, fw: (16,16,5) fp32, out fp32.
//
// R12 = R5 champion (157us) with ONE change: staging is split into
//   Region 1: issue ALL global loads (weights + 80 tile + 8 tail) into
//             named, simultaneously-live registers
//   sched_barrier(0)   <- hard fence: compiler cannot sink loads below or
//                         hoist converts above => cannot recycle dest regs
//                         => one ~900cy latency exposure instead of ~80
//   Region 2: cvt_pk -> ds_write, then barrier, then R5 hot loop.
// Mappings verbatim from verified rounds (R5 staging/frags; R6/R10/R11
// swapped-operand MFMA + dwordx4 store).

#define HH    512
#define WW    512
#define CH    16
#define KK    5
#define IMG   (HH * WW)
#define CHIMG (CH * IMG)
#define RI    20
#define WI    68

typedef __attribute__((ext_vector_type(8))) short bf16x8;
typedef __attribute__((ext_vector_type(4))) float f32x4;
typedef __attribute__((ext_vector_type(4))) int   i32x4;

union I4S8 { i32x4 i; bf16x8 s; };

__device__ __forceinline__ unsigned cvt_pk_bf16(float lo, float hi) {
    unsigned r;
    asm("v_cvt_pk_bf16_f32 %0, %1, %2" : "=v"(r) : "v"(lo), "v"(hi));
    return r;
}

// NOTE (R2): never cap VGPRs via __launch_bounds__ min-waves — acc spills.
// ~135 VGPR peak here is intentional (88 staged values live at the fence);
// occupancy is LDS-capped at 3 blocks/CU either way.
__global__ __launch_bounds__(256)
void diag_conv_mfma(const float* __restrict__ x,
                    const float* __restrict__ fw,
                    float* __restrict__ out)
{
    __shared__ i32x4 xl[2 * RI * WI];   // 43520 B -> 3 blocks/CU

    const int tid  = threadIdx.x;
    const int wv   = tid >> 6;
    const int lane = tid & 63;

    // Bijective XCD swizzle: 4096 blocks = 8 XCDs x 512 contiguous (2 images).
    const int bid = blockIdx.x;
    const int swz = ((bid & 7) << 9) | (bid >> 3);
    const int n  = swz >> 8;
    const int ht = (swz >> 3) & 31;
    const int wt = swz & 7;
    const int h0 = ht * 16;
    const int w0 = wt * 64;

    const float* __restrict__ xn = x + (size_t)n * CHIMG;

    const int px  = lane & 15;
    const int ihl = (lane >> 4) & 1;
    const int tb  = lane >> 5;

    // ================= REGION 1: issue ALL global loads =================
    // (a) weight fragment raw values: 24 loads (tap>=KK lanes load tap 0,
    //     zeroed at convert time)
    float wqv[3][8];
    bool  wok[3];
#pragma unroll
    for (int s = 0; s < 3; ++s) {
        const int tap = 2 * s + tb;
        wok[s] = (tap < KK);
        const float* __restrict__ wp =
            fw + ((size_t)px * CH + ihl * 8) * KK + (wok[s] ? tap : 0);
#pragma unroll
        for (int q = 0; q < 8; ++q) wqv[s][q] = wp[q * KK];
    }

    // (b) main tile: 10 units x 8 channels, 32-bit offsets off SGPR base
    unsigned off[10];
    bool     oku[10];
#pragma unroll
    for (int u = 0; u < 10; ++u) {
        const int unit = u * 4 + wv;
        const int ri = unit >> 1;
        const int ih = unit & 1;
        const int r  = h0 - 2 + ri;
        const int w  = w0 - 2 + lane;
        oku[u] = ((unsigned)r < (unsigned)HH) & ((unsigned)w < (unsigned)WW);
        const int rc = r < 0 ? 0 : (r > HH - 1 ? HH - 1 : r);
        const int wc = w < 0 ? 0 : (w > WW - 1 ? WW - 1 : w);
        off[u] = (unsigned)(ih * 8 * IMG + rc * WW + wc);
    }
    float rv[10][8];
#pragma unroll
    for (int u = 0; u < 10; ++u)
#pragma unroll
        for (int j = 0; j < 8; ++j)
            rv[u][j] = xn[off[u] + (unsigned)(j * IMG)];

    // (c) tail px 64..67
    float tv[8];
    bool  tok   = false;
    int   tsite = 0;
    if (tid < 160) {
        const int ri  = tid >> 3;
        const int rem = tid & 7;
        const int wi  = 64 + (rem & 3);
        const int ih  = rem >> 2;
        const int r   = h0 - 2 + ri;
        const int w   = w0 - 2 + wi;
        tok = ((unsigned)r < (unsigned)HH) & ((unsigned)w < (unsigned)WW);
        const int rc = r < 0 ? 0 : (r > HH - 1 ? HH - 1 : r);
        const int wc = w < 0 ? 0 : (w > WW - 1 ? WW - 1 : w);
        const unsigned toff = (unsigned)(ih * 8 * IMG + rc * WW + wc);
        tsite = (ri * 2 + ih) * WI + wi;
#pragma unroll
        for (int j = 0; j < 8; ++j) tv[j] = xn[toff + (unsigned)(j * IMG)];
    }

    __builtin_amdgcn_sched_barrier(0);   // <-- the experiment

    // ================= REGION 2: convert + LDS writes =================
    bf16x8 afrag[3];
#pragma unroll
    for (int s = 0; s < 3; ++s) {
        I4S8 a;
        a.i.x = (int)cvt_pk_bf16(wqv[s][0], wqv[s][1]);
        a.i.y = (int)cvt_pk_bf16(wqv[s][2], wqv[s][3]);
        a.i.z = (int)cvt_pk_bf16(wqv[s][4], wqv[s][5]);
        a.i.w = (int)cvt_pk_bf16(wqv[s][6], wqv[s][7]);
        if (!wok[s]) a.i = (i32x4){0, 0, 0, 0};
        afrag[s] = a.s;
    }
#pragma unroll
    for (int u = 0; u < 10; ++u) {
        const int unit = u * 4 + wv;
        float v[8];
#pragma unroll
        for (int j = 0; j < 8; ++j) v[j] = oku[u] ? rv[u][j] : 0.f;
        i32x4 pk;
        pk.x = (int)cvt_pk_bf16(v[0], v[1]);
        pk.y = (int)cvt_pk_bf16(v[2], v[3]);
        pk.z = (int)cvt_pk_bf16(v[4], v[5]);
        pk.w = (int)cvt_pk_bf16(v[6], v[7]);
        xl[unit * WI + lane] = pk;
    }
    if (tid < 160) {
        float v[8];
#pragma unroll
        for (int j = 0; j < 8; ++j) v[j] = tok ? tv[j] : 0.f;
        i32x4 pk;
        pk.x = (int)cvt_pk_bf16(v[0], v[1]);
        pk.y = (int)cvt_pk_bf16(v[2], v[3]);
        pk.z = (int)cvt_pk_bf16(v[4], v[5]);
        pk.w = (int)cvt_pk_bf16(v[6], v[7]);
        xl[tsite] = pk;
    }

    __syncthreads();

    // ================= hot loop: R5 geometry, R6/R10/R11-verified mapping ===
    f32x4 acc[4][4];
#pragma unroll
    for (int yy = 0; yy < 4; ++yy)
#pragma unroll
        for (int g = 0; g < 4; ++g) acc[yy][g] = (f32x4){0.f, 0.f, 0.f, 0.f};

    const int ybase = wv * 4;
#pragma unroll
    for (int yy = 0; yy < 4; ++yy) {
#pragma unroll
        for (int s = 0; s < 3; ++s) {
            const int tap = 2 * s + tb;
            int ri = ybase + yy + tap;
            ri = ri > RI - 1 ? RI - 1 : ri;           // tap-5 pad lanes only
            const int c = ri * 2 + ihl;
#pragma unroll
            for (int g = 0; g < 4; ++g) {
                int wi = g * 16 + px + tap;
                wi = wi > WI - 1 ? WI - 1 : wi;       // tap-5 pad lanes only
                I4S8 b;
                b.i = xl[c * WI + wi];                // ds_read_b128
                acc[yy][g] = __builtin_amdgcn_mfma_f32_16x16x32_bf16(
                    b.s, afrag[s], acc[yy][g], 0, 0, 0);   // A=X', B=W'
            }
        }
    }

    // store: D col = o = lane&15, row = px = (lane>>4)*4+reg -> dwordx4
    float* __restrict__ on = out + (size_t)n * CHIMG;
    const int o  = lane & 15;
    const int pq = (lane >> 4) << 2;
#pragma unroll
    for (int yy = 0; yy < 4; ++yy) {
        const int h = h0 + ybase + yy;
#pragma unroll
        for (int g = 0; g < 4; ++g) {
            float* __restrict__ dst =
                on + (size_t)o * IMG + (size_t)h * WW + (w0 + g * 16 + pq);
            *(f32x4*)dst = acc[yy][g];
        }
    }
}

extern "C" void kernel_launch(void* const* d_in, const int* in_sizes, int n_in,
                              void* d_out, int out_size, void* d_ws, size_t ws_size,
                              hipStream_t stream)
{
    const float* x  = (const float*)d_in[0];
    const float* fw = (const float*)d_in[1];
    float* out      = (float*)d_out;

    // 4096 blocks = 16 n x 32 ht x 8 wt
    diag_conv_mfma<<<dim3(4096), dim3(256), 0, stream>>>(x, fw, out);
}